// Round 8
// baseline (199.487 us; speedup 1.0000x reference)
//
#include <hip/hip_runtime.h>
#include <hip/hip_bf16.h>

// Problem constants: B=32, S=512, D=256, H=8, DH=32
#define SCALE_QK 0.17677669529663687f  // 1/sqrt(32)

typedef __attribute__((ext_vector_type(8))) short short8;  // 8 bf16 (4 VGPRs)
typedef __attribute__((ext_vector_type(4))) float f32x4;

__device__ __forceinline__ ushort f2bf(float f) {  // fp32 -> bf16 RNE
  unsigned u = __float_as_uint(f);
  return (ushort)((u + 0x7FFF + ((u >> 16) & 1)) >> 16);
}

// packed fp32x2 -> bf16x2 (RNE), one VALU op (gfx950); attn epilogue only.
__device__ __forceinline__ unsigned cvt_pk_bf16(float lo, float hi) {
  unsigned r;
  asm("v_cvt_pk_bf16_f32 %0, %1, %2" : "=v"(r) : "v"(lo), "v"(hi));
  return r;
}

template <int CTRL>
__device__ __forceinline__ float dpp_movf(float x) {
  return __int_as_float(
      __builtin_amdgcn_update_dpp(0, __float_as_int(x), CTRL, 0xF, 0xF, true));
}
__device__ __forceinline__ float dpp_sum16(float x) {
  x += dpp_movf<0xB1>(x);
  x += dpp_movf<0x4E>(x);
  x += dpp_movf<0x141>(x);
  x += dpp_movf<0x140>(x);
  return x;
}
__device__ __forceinline__ float dpp_max16(float x) {
  x = fmaxf(x, dpp_movf<0xB1>(x));
  x = fmaxf(x, dpp_movf<0x4E>(x));
  x = fmaxf(x, dpp_movf<0x141>(x));
  x = fmaxf(x, dpp_movf<0x140>(x));
  return x;
}

// Exact merge of two sorted triples (A0>=A1>=A2), (B0>=B1>=B2) -> top-3 of
// union into A. Third-place needs A2/B2 only when one list supplies top-2.
#define MERGE3(A0, A1, A2, B0, B1, B2)                               \
  {                                                                  \
    const float m0_ = fmaxf(A0, B0), t_ = fminf(A0, B0);             \
    const float u_ = fmaxf(A1, B1), v_ = fminf(A1, B1);              \
    const float X_ = (A1 >= B0) ? A2 : ((B1 >= A0) ? B2 : -3e38f);   \
    A2 = fmaxf(fmaxf(v_, fminf(t_, u_)), X_);                        \
    A1 = fmaxf(t_, u_);                                              \
    A0 = m0_;                                                        \
  }

// ---------------------------------------------------------------------------
// Fragment-chunk layout ("frag"): element (row,k) of a [R][K] bf16 matrix at
//   chunk = (row>>4)*(K/32) + (k>>5)
//   off   = chunk*512 + ((k>>3)&3)*128 + (row&15)*8 + (k&7)       [ushorts]
// A wave fragment (16 rows x 32 k) is then ONE contiguous 1KB load at
//   base + chunk*512 + lane*8   (lane = quad*16 + l15).
// ---------------------------------------------------------------------------

// prep: blocks [0,2112): convert x|Wq|Wk to frag layout, one 1KB chunk/wave
// (contiguous 16B/lane writes). Blocks [2112,2368): Wvo = Wo.Wv (frag bf16),
// bvo = Wo.bv + bo (block-parallel reduce).
__global__ __launch_bounds__(256) void prep(
    const float *__restrict__ x, const float *__restrict__ w0,
    const float *__restrict__ w1, const float *__restrict__ Wo,
    const float *__restrict__ Wv, const float *__restrict__ bv,
    const float *__restrict__ bo, ushort *__restrict__ xbf,
    ushort *__restrict__ wbf, ushort *__restrict__ wvo,
    float *__restrict__ bvo) {
  __shared__ float tmp[256];
  const int tid = threadIdx.x;
  if (blockIdx.x < 2112) {
    const int w = tid >> 6, lane = tid & 63;
    const int quad = lane >> 4, l15 = lane & 15;
    const int chunk = blockIdx.x * 4 + w;  // [0, 8448)
    const int cc = chunk < 8192 ? chunk : chunk - 8192;
    const int rt = cc >> 3, kt = chunk & 7;
    const int row = rt * 16 + l15;
    const float *srcp;
    ushort *dstp;
    if (chunk < 8192) {
      srcp = x + (long)row * 256;
      dstp = xbf + (long)chunk * 512;
    } else {
      srcp = row < 256 ? w0 + (long)row * 256 : w1 + (long)(row - 256) * 256;
      dstp = wbf + (long)cc * 512;
    }
    const float4 v0 = *(const float4 *)(srcp + kt * 32 + quad * 8);
    const float4 v1 = *(const float4 *)(srcp + kt * 32 + quad * 8 + 4);
    short8 o = {(short)f2bf(v0.x), (short)f2bf(v0.y), (short)f2bf(v0.z),
                (short)f2bf(v0.w), (short)f2bf(v1.x), (short)f2bf(v1.y),
                (short)f2bf(v1.z), (short)f2bf(v1.w)};
    *(short8 *)(dstp + lane * 8) = o;
  } else {
    const int e = blockIdx.x - 2112, m = tid;
    float a0 = 0.f, a1 = 0.f, a2 = 0.f, a3 = 0.f;
#pragma unroll 4
    for (int d = 0; d < 256; d += 8) {
      const float4 wo0 = *(const float4 *)(Wo + e * 256 + d);      // uniform
      const float4 wo1 = *(const float4 *)(Wo + e * 256 + d + 4);  // uniform
      a0 += wo0.x * Wv[(d + 0) * 256 + m];
      a1 += wo0.y * Wv[(d + 1) * 256 + m];
      a2 += wo0.z * Wv[(d + 2) * 256 + m];
      a3 += wo0.w * Wv[(d + 3) * 256 + m];
      a0 += wo1.x * Wv[(d + 4) * 256 + m];
      a1 += wo1.y * Wv[(d + 5) * 256 + m];
      a2 += wo1.z * Wv[(d + 6) * 256 + m];
      a3 += wo1.w * Wv[(d + 7) * 256 + m];
    }
    const long off = ((long)(e >> 4) * 8 + (m >> 5)) * 512 +
                     ((m >> 3) & 3) * 128 + (e & 15) * 8 + (m & 7);
    wvo[off] = f2bf((a0 + a1) + (a2 + a3));
    tmp[m] = Wo[e * 256 + m] * bv[m];
    __syncthreads();
    if (m < 64) {
      float q = tmp[m] + tmp[m + 64] + tmp[m + 128] + tmp[m + 192];
      q = dpp_sum16(q);
      const float r =
          __shfl(q, 0) + __shfl(q, 16) + __shfl(q, 32) + __shfl(q, 48);
      if (m == 0) bvo[e] = r + bo[e];
    }
  }
}

// 128x(16*NJ) NT tile on frag operands, K=256 (8 kTiles). Every load is one
// contiguous 1KB wave-load; every store one contiguous wave-store.
// MODE 1: combined Q|K projection (frag out).  MODE 2: uT (frag out).
template <int NJ, int MODE>
__device__ __forceinline__ void gemm_body(
    const ushort *__restrict__ Yf, const ushort *__restrict__ Xf,
    const float *__restrict__ bA, const float *__restrict__ bB,
    ushort *__restrict__ C0, ushort *__restrict__ C1, int yrt, int xrt0,
    int bx, int by, int b, int w, int quad, int l15, int lane) {
  const ushort *yb0 = Yf + (long)yrt * 8 * 512 + lane * 8;
  const ushort *xb[NJ];
#pragma unroll
  for (int nt = 0; nt < NJ; ++nt)
    xb[nt] = Xf + (long)(xrt0 + nt) * 8 * 512 + lane * 8;

  f32x4 acc[2][NJ] = {};
#pragma unroll 2
  for (int kt = 0; kt < 8; ++kt) {
    const short8 ya = *(const short8 *)(yb0 + kt * 512);
    const short8 yc = *(const short8 *)(yb0 + 32 * 512 + kt * 512);
#pragma unroll
    for (int nt = 0; nt < NJ; ++nt) {
      const short8 xf = *(const short8 *)(xb[nt] + kt * 512);
      acc[0][nt] = __builtin_amdgcn_mfma_f32_16x16x32_bf16(xf, ya, acc[0][nt], 0, 0, 0);
      acc[1][nt] = __builtin_amdgcn_mfma_f32_16x16x32_bf16(xf, yc, acc[1][nt], 0, 0, 0);
    }
  }
#pragma unroll
  for (int side = 0; side < 2; ++side) {
#pragma unroll
    for (int nt = 0; nt < NJ; ++nt) {
      const int iLoc = bx * 128 + w * 16 + 64 * side + l15;
      const f32x4 a = acc[side][nt];
      if (MODE == 1) {
        const int col0 = by * 128 + 16 * nt + 4 * quad;
        const int cq = col0 & 255;
        const float4 bs = *(const float4 *)((col0 < 256 ? bA : bB) + cq);
        const float scl = col0 < 256 ? SCALE_QK : 1.0f;
        ushort *base = col0 < 256 ? C0 : C1;
        const int h = cq >> 5, e = cq & 31;
        const long off =
            ((long)((iLoc >> 9) * 8 + h) * 32 + ((iLoc & 511) >> 4)) * 512 +
            ((e >> 3) & 3) * 128 + l15 * 8 + (e & 7);
        ushort4 st;
        st.x = f2bf((a[0] + bs.x) * scl);
        st.y = f2bf((a[1] + bs.y) * scl);
        st.z = f2bf((a[2] + bs.z) * scl);
        st.w = f2bf((a[3] + bs.w) * scl);
        *(ushort4 *)(base + off) = st;
      } else {
        const int col0 = by * 64 + 16 * nt + 4 * quad;
        const float bd = bA[iLoc];
        const long off = (long)b * 131072 +
                         ((long)(iLoc >> 4) * 16 + (col0 >> 5)) * 512 +
                         ((col0 >> 3) & 3) * 128 + l15 * 8 + (col0 & 7);
        ushort4 st;
        st.x = f2bf(a[0] + bd); st.y = f2bf(a[1] + bd);
        st.z = f2bf(a[2] + bd); st.w = f2bf(a[3] + bd);
        *(ushort4 *)(C0 + off) = st;
      }
    }
  }
}

// Both projection GEMMs, one launch; same-Y-panel blocks at gid stride 128/32
// (both == 0 mod 8) -> same XCD L2.
__global__ __launch_bounds__(256, 2) void gemm_all(
    const ushort *__restrict__ xbf, const ushort *__restrict__ wqk,
    const ushort *__restrict__ wvo, const float *__restrict__ bq,
    const float *__restrict__ bk, const float *__restrict__ bvo,
    ushort *__restrict__ qbf, ushort *__restrict__ kbf,
    ushort *__restrict__ uT) {
  const int tid = threadIdx.x;
  const int w = tid >> 6, lane = tid & 63;
  const int quad = lane >> 4, l15 = lane & 15;
  const int gid = blockIdx.x;
  if (gid < 512) {
    const int bx = gid & 127, by = gid >> 7;
    gemm_body<8, 1>(xbf, wqk, bq, bk, qbf, kbf, bx * 8 + w, by * 8, bx, by, 0,
                    w, quad, l15, lane);
  } else {
    const int id2 = gid - 512;
    const int b = id2 & 31, bx = (id2 >> 5) & 1, by = id2 >> 6;
    gemm_body<4, 2>(wvo, xbf, bvo, nullptr, uT, nullptr, bx * 8 + w,
                    b * 32 + by * 4, bx, by, b, w, quad, l15, lane);
  }
}

// Fused scores + diag-poke + sparsemax + head-average + out-GEMM.
// R8: (a) top-3 scan via v_med3_f32 insertion (3 ops/elem, was 5; identity
// case-verified), 2 chains + 1 merge (was 4 + 3); (b) p-tile bf16 conversion
// via v_cvt_pk_bf16_f32 (16 ops, was ~128). attn is VALU-issue-bound
// (R7: VALUBusy 86%, traffic exactly algorithmic), so cuts are instructions.
__global__ __launch_bounds__(256, 2) void attn_sparsemax_fused(
    const ushort *__restrict__ Q, const ushort *__restrict__ K,
    const ushort *__restrict__ U, float *__restrict__ avg,
    float *__restrict__ out) {
  __shared__ f32x4 sc[16 * 128];  // 32 KB: scores; then p-tile | out-stage
  const int tid = threadIdx.x;
  const int w = tid >> 6, lane = tid & 63;
  const int quad = lane >> 4, l15 = lane & 15;
  const int id = blockIdx.x;
  const int b = (id & 7) | (((id >> 3) & 3) << 3);  // batch -> XCD id&7
  const int s0 = (id >> 5) * 16;
  const int myrow = 4 * w + quad;
  const int sglob = s0 + myrow;
  const int rdbase = myrow * 128 + (l15 ^ (myrow & 7));
  const int dcol = s0 + l15;
  const int pokeIdx = 4 * (l15 * 128 + ((dcol >> 2) ^ (l15 & 7))) + (dcol & 3);
  const bool poker = (w == (s0 >> 7)) && (quad == 0);

  // frag bases: per (b,h) block = 32 chunks x 512; head stride 16384.
  const ushort *qb = Q + ((long)(b * 8) * 32 + (s0 >> 4)) * 512 + lane * 8;
  const ushort *kb = K + ((long)(b * 8) * 32 + w * 8) * 512 + lane * 8;
  short8 bq = *(const short8 *)qb;  // head 0
  short8 ak[8];
#pragma unroll
  for (int jl = 0; jl < 8; ++jl) ak[jl] = *(const short8 *)(kb + jl * 512);

  float avgacc[8][4] = {};
#pragma unroll 1
  for (int h = 0; h < 8; ++h) {
    f32x4 acc[8];
    __builtin_amdgcn_s_setprio(1);
#pragma unroll
    for (int jl = 0; jl < 8; ++jl)
      acc[jl] = __builtin_amdgcn_mfma_f32_16x16x32_bf16(
          ak[jl], bq, (f32x4){0.f, 0.f, 0.f, 0.f}, 0, 0, 0);
    __builtin_amdgcn_s_setprio(0);
    __syncthreads();
#pragma unroll
    for (int jl = 0; jl < 8; ++jl) {
      const int ch = 32 * w + 4 * jl + quad;
      sc[l15 * 128 + (ch ^ (l15 & 7))] = acc[jl];
    }
    if (poker) ((float *)sc)[pokeIdx] = -1e30f;  // same-wave DS order
    __syncthreads();
    // prefetch next head's fragments; hidden under the solve
    if (h < 7) {
      bq = *(const short8 *)(qb + (h + 1) * 16384);
#pragma unroll
      for (int jl = 0; jl < 8; ++jl)
        ak[jl] = *(const short8 *)(kb + (h + 1) * 16384 + jl * 512);
    }
    f32x4 z[8];
#pragma unroll
    for (int c = 0; c < 8; ++c) z[c] = sc[rdbase + 16 * c];
    // top-3 scan via med3 insertion: A0'=max(A0,v), A1'=med3(A0,A1,v),
    // A2'=med3(A1,A2,v). 2 independent 16-elem chains + 1 exact merge.
    float q0a[2], q1a[2], q2a[2];
#pragma unroll
    for (int j = 0; j < 2; ++j) {
      float A0 = -3e38f, A1 = -3e38f, A2 = -3e38f;
#pragma unroll
      for (int c = 4 * j; c < 4 * j + 4; ++c)
#pragma unroll
        for (int r = 0; r < 4; ++r) {
          const float v = z[c][r];
          const float o0 = A0, o1 = A1;
          A0 = fmaxf(o0, v);
          A1 = __builtin_amdgcn_fmed3f(o0, o1, v);
          A2 = __builtin_amdgcn_fmed3f(o1, A2, v);
        }
      q0a[j] = A0; q1a[j] = A1; q2a[j] = A2;
    }
    MERGE3(q0a[0], q1a[0], q2a[0], q0a[1], q1a[1], q2a[1]);
    const float q0 = q0a[0], q1 = q1a[0], q2 = q2a[0];
    const float M = dpp_max16(q0);
    const float thr = M - 1.0f;
    float tau = thr;
    float cOld = -1.f;
    if (__any(q2 > thr)) {
      // slow path: full scan, split partial sums for ILP
#pragma unroll 1
      for (int it = 0; it < 32; ++it) {
        float ss[4] = {0.f, 0.f, 0.f, 0.f}, cc[4] = {0.f, 0.f, 0.f, 0.f};
#pragma unroll
        for (int j = 0; j < 4; ++j)
#pragma unroll
          for (int c = 2 * j; c < 2 * j + 2; ++c)
#pragma unroll
            for (int r = 0; r < 4; ++r) {
              const bool p = z[c][r] > tau;
              ss[j] += p ? z[c][r] : 0.f;
              cc[j] += p ? 1.f : 0.f;
            }
        float s = (ss[0] + ss[1]) + (ss[2] + ss[3]);
        float c = (cc[0] + cc[1]) + (cc[2] + cc[3]);
        s = dpp_sum16(s);
        c = dpp_sum16(c);
        const bool stable = (c == cOld);
        if (__all(stable)) break;
        if (!stable) {
          tau = (s - 1.f) / c;
          cOld = c;
        }
      }
    } else {
      // fast path: support per lane within {q0,q1}; tau monotone >= thr.
#pragma unroll 1
      for (int it = 0; it < 32; ++it) {
        const bool p0 = q0 > tau, p1 = q1 > tau;
        float s = (p0 ? q0 : 0.f) + (p1 ? q1 : 0.f);
        float c = (p0 ? 1.f : 0.f) + (p1 ? 1.f : 0.f);
        s = dpp_sum16(s);
        c = dpp_sum16(c);
        const bool stable = (c == cOld);
        if (__all(stable)) break;
        if (!stable) {
          tau = (s - 1.f) / c;
          cOld = c;
        }
      }
    }
#pragma unroll
    for (int c = 0; c < 8; ++c)
#pragma unroll
      for (int r = 0; r < 4; ++r)
        avgacc[c][r] += fmaxf(z[c][r] - tau, 0.f);
  }
  // avg write (fp32) + bf16 p-tile into first 16KB of LDS
  __syncthreads();
  ushort *pl = (ushort *)sc;
  float *dst = avg + ((b * 512 + sglob) << 9) + 4 * l15;
#pragma unroll
  for (int c = 0; c < 8; ++c) {
    float4 o;
    o.x = avgacc[c][0] * 0.125f;
    o.y = avgacc[c][1] * 0.125f;
    o.z = avgacc[c][2] * 0.125f;
    o.w = avgacc[c][3] * 0.125f;
    *(float4 *)(dst + 64 * c) = o;
    uint2 pv;
    pv.x = cvt_pk_bf16(o.x, o.y);
    pv.y = cvt_pk_bf16(o.z, o.w);
    *(uint2 *)((char *)pl +
               ((myrow * 1024 + 128 * c + 8 * l15) ^ ((myrow & 7) << 4))) = pv;
  }
  __syncthreads();
  // out = avg . u : wave w covers e in [64w, 64w+64). U frag loads contiguous.
  const ushort *ubw = U + (long)b * 131072 + (long)(4 * w) * 16 * 512 + lane * 8;
  f32x4 oacc[4] = {{0.f, 0.f, 0.f, 0.f},
                   {0.f, 0.f, 0.f, 0.f},
                   {0.f, 0.f, 0.f, 0.f},
                   {0.f, 0.f, 0.f, 0.f}};
#pragma unroll
  for (int ks = 0; ks < 16; ++ks) {
    const short8 pf = *(const short8 *)(
        (char *)pl + (l15 * 1024 + ((ks * 64 + quad * 16) ^ ((l15 & 7) << 4))));
    __builtin_amdgcn_s_setprio(1);
#pragma unroll
    for (int nt = 0; nt < 4; ++nt) {
      const short8 uf = *(const short8 *)(ubw + (long)(nt * 16 + ks) * 512);
      oacc[nt] = __builtin_amdgcn_mfma_f32_16x16x32_bf16(uf, pf, oacc[nt], 0, 0, 0);
    }
    __builtin_amdgcn_s_setprio(0);
  }
  // stage out tile in second 16KB (disjoint from p-tile), then linear write
  char *obase = (char *)sc + 16384;
#pragma unroll
  for (int nt = 0; nt < 4; ++nt) {
    const int c4 = 16 * w + 4 * nt + quad;
    float4 st;
    st.x = oacc[nt][0]; st.y = oacc[nt][1];
    st.z = oacc[nt][2]; st.w = oacc[nt][3];
    *(float4 *)(obase + l15 * 1024 + ((c4 * 16) ^ ((l15 & 7) << 4))) = st;
  }
  __syncthreads();
  {
    const int row = tid >> 4, cb = tid & 15;
    float *og = out + ((long)b * 512 + s0 + row) * 256 + cb * 16;
#pragma unroll
    for (int k = 0; k < 4; ++k) {
      const float4 vv = *(const float4 *)(
          obase + row * 1024 + (((cb * 4 + k) * 16) ^ ((row & 7) << 4)));
      *(float4 *)(og + k * 4) = vv;
    }
  }
}

extern "C" void kernel_launch(void* const* d_in, const int* in_sizes, int n_in,
                              void* d_out, int out_size, void* d_ws, size_t ws_size,
                              hipStream_t stream) {
  const float *x  = (const float *)d_in[0];
  const float *Wq = (const float *)d_in[1];
  const float *bq = (const float *)d_in[2];
  const float *Wk = (const float *)d_in[3];
  const float *bk = (const float *)d_in[4];
  const float *Wv = (const float *)d_in[5];
  const float *bv = (const float *)d_in[6];
  const float *Wo = (const float *)d_in[7];
  const float *bo = (const float *)d_in[8];

  float *out = (float *)d_out;                 // [B,S,D]
  float *avg = out + 32 * 512 * 256;           // [B,S,S] fp32

  // ws (ushort units), all frag-chunk layouts:
  ushort *ws16 = (ushort *)d_ws;
  ushort *xbf = ws16;                          // 8192 chunks (16384x256)
  ushort *qbf = ws16 + 4194304;                // (b,h): 32 chunks (512x32)
  ushort *kbf = ws16 + 8388608;
  ushort *uT  = ws16 + 12582912;               // per b: 256 chunks (256x512)
  ushort *wbf = ws16 + 16777216;               // wqk 256 chunks | wvo 128
  float  *bvo = (float *)(ws16 + 16973824);    // [256] fp32

  prep<<<dim3(2368), dim3(256), 0, stream>>>(x, Wq, Wk, Wo, Wv, bv, bo, xbf,
                                             wbf, wbf + 131072, bvo);
  gemm_all<<<dim3(1024), dim3(256), 0, stream>>>(xbf, wbf, wbf + 131072, bq,
                                                 bk, bvo, qbf, kbf, uT);
  attn_sparsemax_fused<<<dim3(1024), dim3(256), 0, stream>>>(qbf, kbf, uT,
                                                             avg, out);
}

// Round 9
// 167.168 us; speedup vs baseline: 1.1933x; 1.1933x over previous
//
#include <hip/hip_runtime.h>
#include <hip/hip_bf16.h>

// Problem constants: B=32, S=512, D=256, H=8, DH=32
#define SCALE_QK 0.17677669529663687f  // 1/sqrt(32)

typedef __attribute__((ext_vector_type(8))) short short8;  // 8 bf16 (4 VGPRs)
typedef __attribute__((ext_vector_type(4))) float f32x4;

__device__ __forceinline__ ushort f2bf(float f) {  // fp32 -> bf16 RNE
  unsigned u = __float_as_uint(f);
  return (ushort)((u + 0x7FFF + ((u >> 16) & 1)) >> 16);
}

// packed fp32x2 -> bf16x2 (RNE), one VALU op (gfx950); attn epilogue only.
__device__ __forceinline__ unsigned cvt_pk_bf16(float lo, float hi) {
  unsigned r;
  asm("v_cvt_pk_bf16_f32 %0, %1, %2" : "=v"(r) : "v"(lo), "v"(hi));
  return r;
}

template <int CTRL>
__device__ __forceinline__ float dpp_movf(float x) {
  return __int_as_float(
      __builtin_amdgcn_update_dpp(0, __float_as_int(x), CTRL, 0xF, 0xF, true));
}
__device__ __forceinline__ float dpp_sum16(float x) {
  x += dpp_movf<0xB1>(x);
  x += dpp_movf<0x4E>(x);
  x += dpp_movf<0x141>(x);
  x += dpp_movf<0x140>(x);
  return x;
}

// Exact merge of two sorted triples (A0>=A1>=A2), (B0>=B1>=B2) -> top-3 of
// union into A. Third-place needs A2/B2 only when one list supplies top-2.
#define MERGE3(A0, A1, A2, B0, B1, B2)                               \
  {                                                                  \
    const float m0_ = fmaxf(A0, B0), t_ = fminf(A0, B0);             \
    const float u_ = fmaxf(A1, B1), v_ = fminf(A1, B1);              \
    const float X_ = (A1 >= B0) ? A2 : ((B1 >= A0) ? B2 : -3e38f);   \
    A2 = fmaxf(fmaxf(v_, fminf(t_, u_)), X_);                        \
    A1 = fmaxf(t_, u_);                                              \
    A0 = m0_;                                                        \
  }

// Butterfly step: merge this lane's sorted triple with its DPP partner's.
// The 4 ctrls (xor1, xor2, half-mirror, mirror) pair disjoint halves at
// every step, so the final triple is the EXACT row-wide top-3 in all lanes.
#define RMERGE(CTRL)                                                 \
  {                                                                  \
    const float b0_ = dpp_movf<CTRL>(r0);                            \
    const float b1_ = dpp_movf<CTRL>(r1);                            \
    const float b2_ = dpp_movf<CTRL>(r2);                            \
    MERGE3(r0, r1, r2, b0_, b1_, b2_);                               \
  }

// ---------------------------------------------------------------------------
// Fragment-chunk layout ("frag"): element (row,k) of a [R][K] bf16 matrix at
//   chunk = (row>>4)*(K/32) + (k>>5)
//   off   = chunk*512 + ((k>>3)&3)*128 + (row&15)*8 + (k&7)       [ushorts]
// A wave fragment (16 rows x 32 k) is then ONE contiguous 1KB load at
//   base + chunk*512 + lane*8   (lane = quad*16 + l15).
// ---------------------------------------------------------------------------

// prep: blocks [0,2112): convert x|Wq|Wk to frag layout, one 1KB chunk/wave
// (contiguous 16B/lane writes). Blocks [2112,2368): Wvo = Wo.Wv (frag bf16),
// bvo = Wo.bv + bo (block-parallel reduce).
__global__ __launch_bounds__(256) void prep(
    const float *__restrict__ x, const float *__restrict__ w0,
    const float *__restrict__ w1, const float *__restrict__ Wo,
    const float *__restrict__ Wv, const float *__restrict__ bv,
    const float *__restrict__ bo, ushort *__restrict__ xbf,
    ushort *__restrict__ wbf, ushort *__restrict__ wvo,
    float *__restrict__ bvo) {
  __shared__ float tmp[256];
  const int tid = threadIdx.x;
  if (blockIdx.x < 2112) {
    const int w = tid >> 6, lane = tid & 63;
    const int quad = lane >> 4, l15 = lane & 15;
    const int chunk = blockIdx.x * 4 + w;  // [0, 8448)
    const int cc = chunk < 8192 ? chunk : chunk - 8192;
    const int rt = cc >> 3, kt = chunk & 7;
    const int row = rt * 16 + l15;
    const float *srcp;
    ushort *dstp;
    if (chunk < 8192) {
      srcp = x + (long)row * 256;
      dstp = xbf + (long)chunk * 512;
    } else {
      srcp = row < 256 ? w0 + (long)row * 256 : w1 + (long)(row - 256) * 256;
      dstp = wbf + (long)cc * 512;
    }
    const float4 v0 = *(const float4 *)(srcp + kt * 32 + quad * 8);
    const float4 v1 = *(const float4 *)(srcp + kt * 32 + quad * 8 + 4);
    short8 o = {(short)f2bf(v0.x), (short)f2bf(v0.y), (short)f2bf(v0.z),
                (short)f2bf(v0.w), (short)f2bf(v1.x), (short)f2bf(v1.y),
                (short)f2bf(v1.z), (short)f2bf(v1.w)};
    *(short8 *)(dstp + lane * 8) = o;
  } else {
    const int e = blockIdx.x - 2112, m = tid;
    float a0 = 0.f, a1 = 0.f, a2 = 0.f, a3 = 0.f;
#pragma unroll 4
    for (int d = 0; d < 256; d += 8) {
      const float4 wo0 = *(const float4 *)(Wo + e * 256 + d);      // uniform
      const float4 wo1 = *(const float4 *)(Wo + e * 256 + d + 4);  // uniform
      a0 += wo0.x * Wv[(d + 0) * 256 + m];
      a1 += wo0.y * Wv[(d + 1) * 256 + m];
      a2 += wo0.z * Wv[(d + 2) * 256 + m];
      a3 += wo0.w * Wv[(d + 3) * 256 + m];
      a0 += wo1.x * Wv[(d + 4) * 256 + m];
      a1 += wo1.y * Wv[(d + 5) * 256 + m];
      a2 += wo1.z * Wv[(d + 6) * 256 + m];
      a3 += wo1.w * Wv[(d + 7) * 256 + m];
    }
    const long off = ((long)(e >> 4) * 8 + (m >> 5)) * 512 +
                     ((m >> 3) & 3) * 128 + (e & 15) * 8 + (m & 7);
    wvo[off] = f2bf((a0 + a1) + (a2 + a3));
    tmp[m] = Wo[e * 256 + m] * bv[m];
    __syncthreads();
    if (m < 64) {
      float q = tmp[m] + tmp[m + 64] + tmp[m + 128] + tmp[m + 192];
      q = dpp_sum16(q);
      const float r =
          __shfl(q, 0) + __shfl(q, 16) + __shfl(q, 32) + __shfl(q, 48);
      if (m == 0) bvo[e] = r + bo[e];
    }
  }
}

// 128x(16*NJ) NT tile on frag operands, K=256 (8 kTiles). Every load is one
// contiguous 1KB wave-load; every store one contiguous wave-store.
// MODE 1: combined Q|K projection (frag out).  MODE 2: uT (frag out).
template <int NJ, int MODE>
__device__ __forceinline__ void gemm_body(
    const ushort *__restrict__ Yf, const ushort *__restrict__ Xf,
    const float *__restrict__ bA, const float *__restrict__ bB,
    ushort *__restrict__ C0, ushort *__restrict__ C1, int yrt, int xrt0,
    int bx, int by, int b, int w, int quad, int l15, int lane) {
  const ushort *yb0 = Yf + (long)yrt * 8 * 512 + lane * 8;
  const ushort *xb[NJ];
#pragma unroll
  for (int nt = 0; nt < NJ; ++nt)
    xb[nt] = Xf + (long)(xrt0 + nt) * 8 * 512 + lane * 8;

  f32x4 acc[2][NJ] = {};
#pragma unroll 1
  for (int kt = 0; kt < 8; ++kt) {
    const short8 ya = *(const short8 *)(yb0 + kt * 512);
    const short8 yc = *(const short8 *)(yb0 + 32 * 512 + kt * 512);
#pragma unroll
    for (int nt = 0; nt < NJ; ++nt) {
      const short8 xf = *(const short8 *)(xb[nt] + kt * 512);
      acc[0][nt] = __builtin_amdgcn_mfma_f32_16x16x32_bf16(xf, ya, acc[0][nt], 0, 0, 0);
      acc[1][nt] = __builtin_amdgcn_mfma_f32_16x16x32_bf16(xf, yc, acc[1][nt], 0, 0, 0);
    }
  }
#pragma unroll
  for (int side = 0; side < 2; ++side) {
#pragma unroll
    for (int nt = 0; nt < NJ; ++nt) {
      const int iLoc = bx * 128 + w * 16 + 64 * side + l15;
      const f32x4 a = acc[side][nt];
      if (MODE == 1) {
        const int col0 = by * 128 + 16 * nt + 4 * quad;
        const int cq = col0 & 255;
        const float4 bs = *(const float4 *)((col0 < 256 ? bA : bB) + cq);
        const float scl = col0 < 256 ? SCALE_QK : 1.0f;
        ushort *base = col0 < 256 ? C0 : C1;
        const int h = cq >> 5, e = cq & 31;
        const long off =
            ((long)((iLoc >> 9) * 8 + h) * 32 + ((iLoc & 511) >> 4)) * 512 +
            ((e >> 3) & 3) * 128 + l15 * 8 + (e & 7);
        ushort4 st;
        st.x = f2bf((a[0] + bs.x) * scl);
        st.y = f2bf((a[1] + bs.y) * scl);
        st.z = f2bf((a[2] + bs.z) * scl);
        st.w = f2bf((a[3] + bs.w) * scl);
        *(ushort4 *)(base + off) = st;
      } else {
        const int col0 = by * 64 + 16 * nt + 4 * quad;
        const float bd = bA[iLoc];
        const long off = (long)b * 131072 +
                         ((long)(iLoc >> 4) * 16 + (col0 >> 5)) * 512 +
                         ((col0 >> 3) & 3) * 128 + l15 * 8 + (col0 & 7);
        ushort4 st;
        st.x = f2bf(a[0] + bd); st.y = f2bf(a[1] + bd);
        st.z = f2bf(a[2] + bd); st.w = f2bf(a[3] + bd);
        *(ushort4 *)(C0 + off) = st;
      }
    }
  }
}

// Both projection GEMMs, one launch; same-Y-panel blocks at gid stride 128/32
// (both == 0 mod 8) -> same XCD L2.  R6 config (plain bounds, unroll 1) —
// empirically best; R7's (256,2) and R8's unroll-2 both regressed ~3-6 µs.
__global__ __launch_bounds__(256) void gemm_all(
    const ushort *__restrict__ xbf, const ushort *__restrict__ wqk,
    const ushort *__restrict__ wvo, const float *__restrict__ bq,
    const float *__restrict__ bk, const float *__restrict__ bvo,
    ushort *__restrict__ qbf, ushort *__restrict__ kbf,
    ushort *__restrict__ uT) {
  const int tid = threadIdx.x;
  const int w = tid >> 6, lane = tid & 63;
  const int quad = lane >> 4, l15 = lane & 15;
  const int gid = blockIdx.x;
  if (gid < 512) {
    const int bx = gid & 127, by = gid >> 7;
    gemm_body<8, 1>(xbf, wqk, bq, bk, qbf, kbf, bx * 8 + w, by * 8, bx, by, 0,
                    w, quad, l15, lane);
  } else {
    const int id2 = gid - 512;
    const int b = id2 & 31, bx = (id2 >> 5) & 1, by = id2 >> 6;
    gemm_body<4, 2>(wvo, xbf, bvo, nullptr, uT, nullptr, bx * 8 + w,
                    b * 32 + by * 4, bx, by, b, w, quad, l15, lane);
  }
}

// Fused scores + diag-poke + sparsemax + head-average + out-GEMM.
// R9 solve: statistics showed ~35 candidates/row above M-1 (not ~3) — the
// old fast path never fired; every head ran ~5-6 full-scan Michelot iters.
// New: tau_j = (sum top-j - 1)/j is <= tau* for ALL j (tau_j rises to k*,
// falls after), so the EXACT row-wide top-3 (dpp butterfly of MERGE3, all
// partners disjoint) gives a always-valid start tau0 = max(M-1, tau_3) with
// only ~8 candidates/row (~0.5/lane). Per-lane top-4 (med3 chains) lets the
// iteration run on (q0,q1,q2) in registers; wave falls back to full scans
// (also from tau0) only if __any(q3 > tau0) (~10%).
__global__ __launch_bounds__(256, 2) void attn_sparsemax_fused(
    const ushort *__restrict__ Q, const ushort *__restrict__ K,
    const ushort *__restrict__ U, float *__restrict__ avg,
    float *__restrict__ out) {
  __shared__ f32x4 sc[16 * 128];  // 32 KB: scores; then p-tile | out-stage
  const int tid = threadIdx.x;
  const int w = tid >> 6, lane = tid & 63;
  const int quad = lane >> 4, l15 = lane & 15;
  const int id = blockIdx.x;
  const int b = (id & 7) | (((id >> 3) & 3) << 3);  // batch -> XCD id&7
  const int s0 = (id >> 5) * 16;
  const int myrow = 4 * w + quad;
  const int sglob = s0 + myrow;
  const int rdbase = myrow * 128 + (l15 ^ (myrow & 7));
  const int dcol = s0 + l15;
  const int pokeIdx = 4 * (l15 * 128 + ((dcol >> 2) ^ (l15 & 7))) + (dcol & 3);
  const bool poker = (w == (s0 >> 7)) && (quad == 0);

  // frag bases: per (b,h) block = 32 chunks x 512; head stride 16384.
  const ushort *qb = Q + ((long)(b * 8) * 32 + (s0 >> 4)) * 512 + lane * 8;
  const ushort *kb = K + ((long)(b * 8) * 32 + w * 8) * 512 + lane * 8;
  short8 bq = *(const short8 *)qb;  // head 0
  short8 ak[8];
#pragma unroll
  for (int jl = 0; jl < 8; ++jl) ak[jl] = *(const short8 *)(kb + jl * 512);

  float avgacc[8][4] = {};
#pragma unroll 1
  for (int h = 0; h < 8; ++h) {
    f32x4 acc[8];
    __builtin_amdgcn_s_setprio(1);
#pragma unroll
    for (int jl = 0; jl < 8; ++jl)
      acc[jl] = __builtin_amdgcn_mfma_f32_16x16x32_bf16(
          ak[jl], bq, (f32x4){0.f, 0.f, 0.f, 0.f}, 0, 0, 0);
    __builtin_amdgcn_s_setprio(0);
    __syncthreads();
#pragma unroll
    for (int jl = 0; jl < 8; ++jl) {
      const int ch = 32 * w + 4 * jl + quad;
      sc[l15 * 128 + (ch ^ (l15 & 7))] = acc[jl];
    }
    if (poker) ((float *)sc)[pokeIdx] = -1e30f;  // same-wave DS order
    __syncthreads();
    // prefetch next head's fragments; hidden under the solve
    if (h < 7) {
      bq = *(const short8 *)(qb + (h + 1) * 16384);
#pragma unroll
      for (int jl = 0; jl < 8; ++jl)
        ak[jl] = *(const short8 *)(kb + (h + 1) * 16384 + jl * 512);
    }
    f32x4 z[8];
#pragma unroll
    for (int c = 0; c < 8; ++c) z[c] = sc[rdbase + 16 * c];
    // per-lane top-4 via med3 insertion (4 ops/elem; q3 chain case-verified)
    float q0 = -3e38f, q1 = -3e38f, q2 = -3e38f, q3 = -3e38f;
#pragma unroll
    for (int c = 0; c < 8; ++c)
#pragma unroll
      for (int r = 0; r < 4; ++r) {
        const float v = z[c][r];
        const float o0 = q0, o1 = q1, o2 = q2;
        q0 = fmaxf(o0, v);
        q1 = __builtin_amdgcn_fmed3f(o0, o1, v);
        q2 = __builtin_amdgcn_fmed3f(o1, o2, v);
        q3 = __builtin_amdgcn_fmed3f(o2, q3, v);
      }
    // exact row-wide top-3 (butterfly; disjoint partners each step)
    float r0 = q0, r1 = q1, r2 = q2;
    RMERGE(0xB1) RMERGE(0x4E) RMERGE(0x141) RMERGE(0x140)
    const float M = r0;
    const float tau0 = fmaxf(M - 1.0f, (r0 + r1 + r2 - 1.0f) * (1.f / 3.f));
    float tau = tau0;
    float cOld = -1.f;
    if (__any(q3 > tau0)) {
      // slow path: full scans from tau0 (valid superset start)
#pragma unroll 1
      for (int it = 0; it < 32; ++it) {
        float ss[4] = {0.f, 0.f, 0.f, 0.f}, cc[4] = {0.f, 0.f, 0.f, 0.f};
#pragma unroll
        for (int j = 0; j < 4; ++j)
#pragma unroll
          for (int c = 2 * j; c < 2 * j + 2; ++c)
#pragma unroll
            for (int r = 0; r < 4; ++r) {
              const bool p = z[c][r] > tau;
              ss[j] += p ? z[c][r] : 0.f;
              cc[j] += p ? 1.f : 0.f;
            }
        float s = (ss[0] + ss[1]) + (ss[2] + ss[3]);
        float c = (cc[0] + cc[1]) + (cc[2] + cc[3]);
        s = dpp_sum16(s);
        c = dpp_sum16(c);
        const bool stable = (c == cOld);
        if (__all(stable)) break;
        if (!stable) {
          tau = (s - 1.f) / c;
          cOld = c;
        }
      }
    } else {
      // fast path: every lane's candidates above tau0 are within {q0,q1,q2}
      // (q3 <= tau0, tau monotone >= tau0).
#pragma unroll 1
      for (int it = 0; it < 32; ++it) {
        const bool p0 = q0 > tau, p1 = q1 > tau, p2 = q2 > tau;
        float s = (p0 ? q0 : 0.f) + (p1 ? q1 : 0.f) + (p2 ? q2 : 0.f);
        float c = (p0 ? 1.f : 0.f) + (p1 ? 1.f : 0.f) + (p2 ? 1.f : 0.f);
        s = dpp_sum16(s);
        c = dpp_sum16(c);
        const bool stable = (c == cOld);
        if (__all(stable)) break;
        if (!stable) {
          tau = (s - 1.f) / c;
          cOld = c;
        }
      }
    }
#pragma unroll
    for (int c = 0; c < 8; ++c)
#pragma unroll
      for (int r = 0; r < 4; ++r)
        avgacc[c][r] += fmaxf(z[c][r] - tau, 0.f);
  }
  // avg write (fp32) + bf16 p-tile into first 16KB of LDS
  __syncthreads();
  ushort *pl = (ushort *)sc;
  float *dst = avg + ((b * 512 + sglob) << 9) + 4 * l15;
#pragma unroll
  for (int c = 0; c < 8; ++c) {
    float4 o;
    o.x = avgacc[c][0] * 0.125f;
    o.y = avgacc[c][1] * 0.125f;
    o.z = avgacc[c][2] * 0.125f;
    o.w = avgacc[c][3] * 0.125f;
    *(float4 *)(dst + 64 * c) = o;
    uint2 pv;
    pv.x = cvt_pk_bf16(o.x, o.y);
    pv.y = cvt_pk_bf16(o.z, o.w);
    *(uint2 *)((char *)pl +
               ((myrow * 1024 + 128 * c + 8 * l15) ^ ((myrow & 7) << 4))) = pv;
  }
  __syncthreads();
  // out = avg . u : wave w covers e in [64w, 64w+64). U frag loads contiguous.
  const ushort *ubw = U + (long)b * 131072 + (long)(4 * w) * 16 * 512 + lane * 8;
  f32x4 oacc[4] = {{0.f, 0.f, 0.f, 0.f},
                   {0.f, 0.f, 0.f, 0.f},
                   {0.f, 0.f, 0.f, 0.f},
                   {0.f, 0.f, 0.f, 0.f}};
#pragma unroll
  for (int ks = 0; ks < 16; ++ks) {
    const short8 pf = *(const short8 *)(
        (char *)pl + (l15 * 1024 + ((ks * 64 + quad * 16) ^ ((l15 & 7) << 4))));
    __builtin_amdgcn_s_setprio(1);
#pragma unroll
    for (int nt = 0; nt < 4; ++nt) {
      const short8 uf = *(const short8 *)(ubw + (long)(nt * 16 + ks) * 512);
      oacc[nt] = __builtin_amdgcn_mfma_f32_16x16x32_bf16(uf, pf, oacc[nt], 0, 0, 0);
    }
    __builtin_amdgcn_s_setprio(0);
  }
  // stage out tile in second 16KB (disjoint from p-tile), then linear write
  char *obase = (char *)sc + 16384;
#pragma unroll
  for (int nt = 0; nt < 4; ++nt) {
    const int c4 = 16 * w + 4 * nt + quad;
    float4 st;
    st.x = oacc[nt][0]; st.y = oacc[nt][1];
    st.z = oacc[nt][2]; st.w = oacc[nt][3];
    *(float4 *)(obase + l15 * 1024 + ((c4 * 16) ^ ((l15 & 7) << 4))) = st;
  }
  __syncthreads();
  {
    const int row = tid >> 4, cb = tid & 15;
    float *og = out + ((long)b * 512 + s0 + row) * 256 + cb * 16;
#pragma unroll
    for (int k = 0; k < 4; ++k) {
      const float4 vv = *(const float4 *)(
          obase + row * 1024 + (((cb * 4 + k) * 16) ^ ((row & 7) << 4)));
      *(float4 *)(og + k * 4) = vv;
    }
  }
}

extern "C" void kernel_launch(void* const* d_in, const int* in_sizes, int n_in,
                              void* d_out, int out_size, void* d_ws, size_t ws_size,
                              hipStream_t stream) {
  const float *x  = (const float *)d_in[0];
  const float *Wq = (const float *)d_in[1];
  const float *bq = (const float *)d_in[2];
  const float *Wk = (const float *)d_in[3];
  const float *bk = (const float *)d_in[4];
  const float *Wv = (const float *)d_in[5];
  const float *bv = (const float *)d_in[6];
  const float *Wo = (const float *)d_in[7];
  const float *bo = (const float *)d_in[8];

  float *out = (float *)d_out;                 // [B,S,D]
  float *avg = out + 32 * 512 * 256;           // [B,S,S] fp32

  // ws (ushort units), all frag-chunk layouts:
  ushort *ws16 = (ushort *)d_ws;
  ushort *xbf = ws16;                          // 8192 chunks (16384x256)
  ushort *qbf = ws16 + 4194304;                // (b,h): 32 chunks (512x32)
  ushort *kbf = ws16 + 8388608;
  ushort *uT  = ws16 + 12582912;               // per b: 256 chunks (256x512)
  ushort *wbf = ws16 + 16777216;               // wqk 256 chunks | wvo 128
  float  *bvo = (float *)(ws16 + 16973824);    // [256] fp32

  prep<<<dim3(2368), dim3(256), 0, stream>>>(x, Wq, Wk, Wo, Wv, bv, bo, xbf,
                                             wbf, wbf + 131072, bvo);
  gemm_all<<<dim3(1024), dim3(256), 0, stream>>>(xbf, wbf, wbf + 131072, bq,
                                                 bk, bvo, qbf, kbf, uT);
  attn_sparsemax_fused<<<dim3(1024), dim3(256), 0, stream>>>(qbf, kbf, uT,
                                                             avg, out);
}